// Round 4
// baseline (916.694 us; speedup 1.0000x reference)
//
#include <hip/hip_runtime.h>

typedef unsigned short u16;
typedef unsigned int u32;
typedef __attribute__((ext_vector_type(8))) short bf16x8;
typedef __attribute__((ext_vector_type(4))) float f32x4;

#define N_NODES 10000
#define E_EDGES 640000

static __device__ __forceinline__ float b2f(u16 u) {
  union { u32 i; float f; } x; x.i = ((u32)u) << 16; return x.f;
}
static __device__ __forceinline__ u16 f2b(float f) {
  union { float f; u32 i; } x; x.f = f;
  u32 r = x.i + 0x7FFF + ((x.i >> 16) & 1);   // RNE
  return (u16)(r >> 16);
}
// dtype-flagged load: f32 ? float : bf16
static __device__ __forceinline__ float ldf(const void* p, size_t i, int f32) {
  return f32 ? ((const float*)p)[i] : b2f(((const u16*)p)[i]);
}

// ---------------- dtype detect: bf16 data has no exponent >= 140; fp32 low-halves do ----------------
__global__ __launch_bounds__(256) void detect_kernel(const u16* __restrict__ x, int* __restrict__ flag) {
  __shared__ int cnt_s;
  if (threadIdx.x == 0) cnt_s = 0;
  __syncthreads();
  int c = 0;
  for (int i = threadIdx.x; i < 4096; i += 256) {
    int e = (x[i] >> 7) & 255;
    if (e >= 140) c++;
  }
  atomicAdd(&cnt_s, c);
  __syncthreads();
  if (threadIdx.x == 0) flag[0] = (cnt_s > 64) ? 1 : 0;
}

// ---------------- CSR build keyed by (dst*8 + rel) ----------------
__global__ void hist_kernel(const int* __restrict__ ei, const int* __restrict__ et,
                            int E, int* __restrict__ cnt8) {
  int e = blockIdx.x * 256 + threadIdx.x;
  if (e < E) atomicAdd(&cnt8[ei[E + e] * 8 + et[e]], 1);
}

// fused: per-dst totals + exclusive scan + (dst,rel) segment offsets, one block
__global__ __launch_bounds__(256) void segscan_kernel(const int* __restrict__ cnt8,
                                                      int* __restrict__ offs,
                                                      int* __restrict__ cursor) {
  __shared__ int tmp[256];
  const int t = threadIdx.x;
  const int CH = (N_NODES + 255) / 256;   // 40
  const int d0 = t * CH;
  int s = 0;
  for (int j = 0; j < CH; j++) {
    int d = d0 + j;
    if (d < N_NODES) {
      #pragma unroll
      for (int r = 0; r < 8; r++) s += cnt8[d * 8 + r];
    }
  }
  tmp[t] = s;
  __syncthreads();
  for (int od = 1; od < 256; od <<= 1) {
    int a = (t >= od) ? tmp[t - od] : 0;
    __syncthreads();
    tmp[t] += a;
    __syncthreads();
  }
  int run = tmp[t] - s;   // exclusive prefix over this thread's chunk
  for (int j = 0; j < CH; j++) {
    int d = d0 + j;
    if (d < N_NODES) {
      #pragma unroll
      for (int r = 0; r < 8; r++) {
        offs[d * 8 + r] = run;
        cursor[d * 8 + r] = run;
        run += cnt8[d * 8 + r];
      }
    }
  }
  if (t == 255) offs[N_NODES * 8] = tmp[255];
}

__global__ void bucket_kernel(const int* __restrict__ ei, const int* __restrict__ et,
                              int E, int* __restrict__ cursor, int* __restrict__ bucket) {
  int e = blockIdx.x * 256 + threadIdx.x;
  if (e < E) {
    int seg = ei[E + e] * 8 + et[e];
    int pos = atomicAdd(&cursor[seg], 1);
    bucket[pos] = ei[e];   // src only; relation is the segment index
  }
}

// ---------------- transpose (emb -> embT as bf16) ----------------
__global__ void transpose_kernel(const void* __restrict__ in, u16* __restrict__ out,
                                 int R, int C, const int* __restrict__ dflag) {
  __shared__ u16 tile[64][65];
  const int f = dflag[0];
  int r0 = blockIdx.x * 64, c0 = blockIdx.y * 64;
  int t = threadIdx.x;
  #pragma unroll
  for (int k = 0; k < 16; k++) {
    int lin = t + k * 256; int rr = lin >> 6, cc = lin & 63;
    int gr = r0 + rr;
    tile[rr][cc] = (gr < R) ? f2b(ldf(in, (size_t)gr * C + c0 + cc, f)) : (u16)0;
  }
  __syncthreads();
  #pragma unroll
  for (int k = 0; k < 16; k++) {
    int lin = t + k * 256; int rr = lin >> 6, cc = lin & 63;
    int gc = r0 + cc;
    if (gc < R) out[(size_t)(c0 + rr) * R + gc] = tile[cc][rr];
  }
}

// ---------------- W-prep body: WT[o][kcat], kcat = r*I+i (basis rows) then I root rows ----------------
template<int I, int O>
static __device__ __forceinline__ void wprep_body(const void* comp, const void* basis,
                                                  const void* root, u16* WT,
                                                  int f, int blk) {
  const int Kcat = 9 * I;
  int idx = blk * 256 + threadIdx.x;
  if (idx >= Kcat * O) return;
  int o = idx % O;
  int kc = idx / O;
  float v;
  if (kc < 8 * I) {
    int r = kc / I, i = kc % I;
    float s = 0.f;
    #pragma unroll
    for (int b = 0; b < 8; b++)
      s += ldf(comp, r * 8 + b, f) * ldf(basis, ((size_t)b * I + i) * O + o, f);
    v = s;
  } else {
    int i = kc - 8 * I;
    v = ldf(root, (size_t)i * O + o, f);
  }
  WT[(size_t)o * Kcat + kc] = f2b(v);
}

// both layers' W-prep in one dispatch (blocks 0..1151 -> L1, 1152..2303 -> L2)
__global__ void wprep_both_kernel(const void* c1, const void* b1, const void* r1, u16* WT1,
                                  const void* c2, const void* b2, const void* r2, u16* WT2,
                                  const int* __restrict__ dflag) {
  const int f = dflag[0];
  int blk = blockIdx.x;
  if (blk < 1152) wprep_body<128, 256>(c1, b1, r1, WT1, f, blk);
  else            wprep_body<256, 128>(c2, b2, r2, WT2, f, blk - 1152);
}

// ---------------- gather layer 1: 64 threads, u32 channel-pairs, register accumulate ----------------
// s row layout (u16 units): [r*128 + i] = mean over relation-r in-edges; [1024 + i] = own h0 row
__global__ void gather1_kernel(const u16* __restrict__ h, const int* __restrict__ offs,
                               const int* __restrict__ bucket, u16* __restrict__ s) {
  const int d = blockIdx.x, t = threadIdx.x;   // 64 threads
  const u32* __restrict__ h32 = (const u32*)h;  // row stride 64
  u32* s32 = (u32*)s;
  const int sb = d * 8;
  const int b0 = offs[sb], bend = offs[sb + 8];
  const float inv = 1.0f / (float)((bend - b0) > 1 ? (bend - b0) : 1);
  const int base = d * 576;   // 1152/2
  #pragma unroll
  for (int r = 0; r < 8; r++) {
    int j = offs[sb + r], j1 = offs[sb + r + 1];
    float l0 = 0.f, h0a = 0.f, l1 = 0.f, h1a = 0.f, l2 = 0.f, h2a = 0.f, l3 = 0.f, h3a = 0.f;
    for (; j + 3 < j1; j += 4) {
      u32 v0 = h32[(size_t)bucket[j] * 64 + t];
      u32 v1 = h32[(size_t)bucket[j + 1] * 64 + t];
      u32 v2 = h32[(size_t)bucket[j + 2] * 64 + t];
      u32 v3 = h32[(size_t)bucket[j + 3] * 64 + t];
      l0 += b2f((u16)v0); h0a += b2f((u16)(v0 >> 16));
      l1 += b2f((u16)v1); h1a += b2f((u16)(v1 >> 16));
      l2 += b2f((u16)v2); h2a += b2f((u16)(v2 >> 16));
      l3 += b2f((u16)v3); h3a += b2f((u16)(v3 >> 16));
    }
    for (; j < j1; ++j) {
      u32 v = h32[(size_t)bucket[j] * 64 + t];
      l0 += b2f((u16)v); h0a += b2f((u16)(v >> 16));
    }
    float sl = (l0 + l1 + l2 + l3) * inv, sh = (h0a + h1a + h2a + h3a) * inv;
    s32[base + r * 64 + t] = (u32)f2b(sl) | ((u32)f2b(sh) << 16);
  }
  s32[base + 512 + t] = h32[(size_t)d * 64 + t];
}

// ---------------- gather layer 2: 64 threads, uint2 4-channel chunks ----------------
// s row layout (u16 units): [r*256 + i] mean; [2048 + i] own h1 row
__global__ void gather2_kernel(const u16* __restrict__ h, const int* __restrict__ offs,
                               const int* __restrict__ bucket, u16* __restrict__ s) {
  const int d = blockIdx.x, t = threadIdx.x;   // 64 threads
  const uint2* __restrict__ h64 = (const uint2*)h;  // row stride 64
  uint2* s64 = (uint2*)s;
  const int sb = d * 8;
  const int b0 = offs[sb], bend = offs[sb + 8];
  const float inv = 1.0f / (float)((bend - b0) > 1 ? (bend - b0) : 1);
  const int base = d * 576;   // 2304/4
  #pragma unroll
  for (int r = 0; r < 8; r++) {
    int j = offs[sb + r], j1 = offs[sb + r + 1];
    float4 A0 = {0.f, 0.f, 0.f, 0.f}, A1 = A0, A2 = A0, A3 = A0;
    for (; j + 3 < j1; j += 4) {
      uint2 v0 = h64[(size_t)bucket[j] * 64 + t];
      uint2 v1 = h64[(size_t)bucket[j + 1] * 64 + t];
      uint2 v2 = h64[(size_t)bucket[j + 2] * 64 + t];
      uint2 v3 = h64[(size_t)bucket[j + 3] * 64 + t];
      A0.x += b2f((u16)v0.x); A0.y += b2f((u16)(v0.x >> 16)); A0.z += b2f((u16)v0.y); A0.w += b2f((u16)(v0.y >> 16));
      A1.x += b2f((u16)v1.x); A1.y += b2f((u16)(v1.x >> 16)); A1.z += b2f((u16)v1.y); A1.w += b2f((u16)(v1.y >> 16));
      A2.x += b2f((u16)v2.x); A2.y += b2f((u16)(v2.x >> 16)); A2.z += b2f((u16)v2.y); A2.w += b2f((u16)(v2.y >> 16));
      A3.x += b2f((u16)v3.x); A3.y += b2f((u16)(v3.x >> 16)); A3.z += b2f((u16)v3.y); A3.w += b2f((u16)(v3.y >> 16));
    }
    for (; j < j1; ++j) {
      uint2 v = h64[(size_t)bucket[j] * 64 + t];
      A0.x += b2f((u16)v.x); A0.y += b2f((u16)(v.x >> 16)); A0.z += b2f((u16)v.y); A0.w += b2f((u16)(v.y >> 16));
    }
    float sx = (A0.x + A1.x + A2.x + A3.x) * inv;
    float sy = (A0.y + A1.y + A2.y + A3.y) * inv;
    float sz = (A0.z + A1.z + A2.z + A3.z) * inv;
    float sw = (A0.w + A1.w + A2.w + A3.w) * inv;
    uint2 o;
    o.x = (u32)f2b(sx) | ((u32)f2b(sy) << 16);
    o.y = (u32)f2b(sz) | ((u32)f2b(sw) << 16);
    s64[base + r * 64 + t] = o;
  }
  s64[base + 512 + t] = h64[(size_t)d * 64 + t];
}

// ---------------- MFMA GEMM: atomicAdd f32 into outf = A[M,K] * BT[Nout,K]^T, 128x128 tiles ----------------
// A is bf16 unless (dflagA && dflagA[0]) -> fp32 elements, converted during staging.
__global__ __launch_bounds__(256) void gemm_kernel(
    const void* __restrict__ A, int lda,
    const u16* __restrict__ BT, int ldbt,
    int M, int Nout, int K,
    int tiles_per_split, int ktiles_total,
    float* __restrict__ outf,
    const int* __restrict__ dflagA) {
  __shared__ __align__(16) u16 As[128 * 32];
  __shared__ __align__(16) u16 Bs[128 * 32];
  const int f32A = dflagA ? dflagA[0] : 0;
  const int tid = threadIdx.x;
  const int wave = tid >> 6;
  const int lane = tid & 63;
  const int quad = lane >> 4;
  const int l16 = lane & 15;
  const int m0 = blockIdx.x * 128;
  const int n0 = blockIdx.y * 128;
  const int split = blockIdx.z;
  const int wm = (wave >> 1) * 64;
  const int wn = (wave & 1) * 64;

  int kt0 = split * tiles_per_split;
  int kt1 = kt0 + tiles_per_split;
  if (kt1 > ktiles_total) kt1 = ktiles_total;

  f32x4 acc[4][4];
  #pragma unroll
  for (int mi = 0; mi < 4; mi++)
    #pragma unroll
    for (int ni = 0; ni < 4; ni++) {
      f32x4 z = {0.f, 0.f, 0.f, 0.f};
      acc[mi][ni] = z;
    }

  for (int kt = kt0; kt < kt1; ++kt) {
    const int k0 = kt * 32;
    __syncthreads();
    #pragma unroll
    for (int i = 0; i < 2; ++i) {
      int c = tid + i * 256;
      int row = c >> 2, kc = c & 3;
      int kpos = k0 + kc * 8;
      // B tile (always bf16)
      uint4 vb = {0u, 0u, 0u, 0u};
      if (kpos < K) vb = *(const uint4*)(BT + (size_t)(n0 + row) * ldbt + kpos);
      *(uint4*)&Bs[(size_t)c * 8] = vb;
      // A tile
      uint4 va = {0u, 0u, 0u, 0u};
      if (kpos < K) {
        int ga = m0 + row; if (ga > M - 1) ga = M - 1;
        if (!f32A) {
          va = *(const uint4*)((const u16*)A + (size_t)ga * lda + kpos);
        } else {
          const float* Af = (const float*)A + (size_t)ga * lda + kpos;
          float4 f0 = ((const float4*)Af)[0];
          float4 f1 = ((const float4*)Af)[1];
          va.x = (u32)f2b(f0.x) | ((u32)f2b(f0.y) << 16);
          va.y = (u32)f2b(f0.z) | ((u32)f2b(f0.w) << 16);
          va.z = (u32)f2b(f1.x) | ((u32)f2b(f1.y) << 16);
          va.w = (u32)f2b(f1.z) | ((u32)f2b(f1.w) << 16);
        }
      }
      *(uint4*)&As[(size_t)c * 8] = va;
    }
    __syncthreads();

    bf16x8 af[4], bfr[4];
    #pragma unroll
    for (int mi = 0; mi < 4; mi++)
      af[mi] = *(const bf16x8*)&As[(size_t)(wm + mi * 16 + l16) * 32 + quad * 8];
    #pragma unroll
    for (int ni = 0; ni < 4; ni++)
      bfr[ni] = *(const bf16x8*)&Bs[(size_t)(wn + ni * 16 + l16) * 32 + quad * 8];
    #pragma unroll
    for (int mi = 0; mi < 4; mi++)
      #pragma unroll
      for (int ni = 0; ni < 4; ni++)
        acc[mi][ni] = __builtin_amdgcn_mfma_f32_16x16x32_bf16(af[mi], bfr[ni], acc[mi][ni], 0, 0, 0);
  }

  #pragma unroll
  for (int mi = 0; mi < 4; mi++)
    #pragma unroll
    for (int ni = 0; ni < 4; ni++)
      #pragma unroll
      for (int jj = 0; jj < 4; jj++) {
        int row = m0 + wm + mi * 16 + quad * 4 + jj;
        int col = n0 + wn + ni * 16 + l16;
        if (row < M) atomicAdd(&outf[(size_t)row * Nout + col], acc[mi][ni][jj]);
      }
}

// ---------------- finalize: accf (+bias) -> relu -> bf16, 4 elements/thread ----------------
__global__ void finalize_kernel(const float* __restrict__ accf, int count4, int nmask,
                                const void* __restrict__ bias, u16* __restrict__ out,
                                const int* __restrict__ dflag) {
  int i = blockIdx.x * 256 + threadIdx.x;
  if (i >= count4) return;
  const int f = dflag[0];
  float4 v = ((const float4*)accf)[i];
  if (bias) {
    int c = (i * 4) & nmask;
    v.x += ldf(bias, c, f);
    v.y += ldf(bias, c + 1, f);
    v.z += ldf(bias, c + 2, f);
    v.w += ldf(bias, c + 3, f);
  }
  v.x = fmaxf(v.x, 0.f); v.y = fmaxf(v.y, 0.f); v.z = fmaxf(v.z, 0.f); v.w = fmaxf(v.w, 0.f);
  ushort4 o;
  o.x = f2b(v.x); o.y = f2b(v.y); o.z = f2b(v.z); o.w = f2b(v.w);
  *(ushort4*)(out + (size_t)i * 4) = o;
}

// ---------------- decoder: softmax(relu(h2f + bias2) @ wdec); output dtype follows flag ----------------
__global__ __launch_bounds__(256) void decoder_kernel(const float* __restrict__ h2f,
                                                      const void* __restrict__ wdec,
                                                      const void* __restrict__ bias2,
                                                      void* __restrict__ out,
                                                      const int* __restrict__ dflag) {
  __shared__ float w[128 * 32];
  __shared__ float hrow[4][128];
  const int f = dflag[0];
  int t = threadIdx.x;
  for (int i = t; i < 128 * 32; i += 256) w[i] = ldf(wdec, i, f);
  int wv = t >> 6, lane = t & 63;
  int n = blockIdx.x * 4 + wv;   // grid 2500 * 4 waves = 10000 exactly
  float b0 = ldf(bias2, lane * 2, f), b1 = ldf(bias2, lane * 2 + 1, f);
  hrow[wv][lane * 2]     = fmaxf(h2f[(size_t)n * 128 + lane * 2] + b0, 0.f);
  hrow[wv][lane * 2 + 1] = fmaxf(h2f[(size_t)n * 128 + lane * 2 + 1] + b1, 0.f);
  __syncthreads();
  int half = lane >> 5, c = lane & 31;
  float sum = 0.f;
  #pragma unroll 8
  for (int k = 0; k < 64; k++) sum += hrow[wv][half * 64 + k] * w[(half * 64 + k) * 32 + c];
  sum += __shfl_xor(sum, 32);
  float mx = sum;
  #pragma unroll
  for (int m = 16; m >= 1; m >>= 1) mx = fmaxf(mx, __shfl_xor(mx, m));
  float e = __expf(sum - mx);
  float tot = e;
  #pragma unroll
  for (int m = 16; m >= 1; m >>= 1) tot += __shfl_xor(tot, m);
  float p = e / tot;
  if (half == 0) {
    if (f) ((float*)out)[(size_t)n * 32 + c] = p;
    else   ((u16*)out)[(size_t)n * 32 + c] = f2b(p);
  }
}

extern "C" void kernel_launch(void* const* d_in, const int* in_sizes, int n_in,
                              void* d_out, int out_size, void* d_ws, size_t ws_size,
                              hipStream_t stream) {
  const void* x      = d_in[0];
  const int* ei      = (const int*)d_in[1];
  const int* et      = (const int*)d_in[2];
  const void* emb    = d_in[3];
  const void* comp1  = d_in[4];
  const void* basis1 = d_in[5];
  const void* root1  = d_in[6];
  const void* bias1  = d_in[7];
  const void* comp2  = d_in[8];
  const void* basis2 = d_in[9];
  const void* root2  = d_in[10];
  const void* bias2  = d_in[11];
  const void* wdec   = d_in[12];

  const int N = N_NODES, E = E_EDGES;
  const int NSEG = N * 8;
  auto AL = [](size_t b) -> size_t { return (b + 255) & ~(size_t)255; };

  // ---- persistent arena ----
  char* base = (char*)d_ws;
  size_t off = 0;
  auto alloc = [&](size_t b) -> char* { char* p = base + off; off += AL(b); return p; };
  int* dflag   = (int*)alloc(4);
  int* offs    = (int*)alloc((size_t)(NSEG + 1) * 4);
  int* cursor  = (int*)alloc((size_t)NSEG * 4);
  int* bucket  = (int*)alloc((size_t)E * 4);
  u16* h0      = (u16*)alloc((size_t)N * 128 * 2);
  u16* h1      = (u16*)alloc((size_t)N * 256 * 2);
  // zero-initialized region: cnt8 + accumulators (contiguous -> ONE memset)
  size_t zoff0 = off;
  int*   cnt8  = (int*)alloc((size_t)NSEG * 4);
  float* h0f   = (float*)alloc((size_t)N * 128 * 4);
  float* h1f   = (float*)alloc((size_t)N * 256 * 4);
  float* h2f   = (float*)alloc((size_t)N * 128 * 4);
  size_t zbytes = off - zoff0;
  u16* WT1     = (u16*)alloc((size_t)256 * 1152 * 2);
  u16* WT2     = (u16*)alloc((size_t)128 * 2304 * 2);
  u16* embT    = (u16*)alloc((size_t)128 * N * 2);
  u16* s1      = (u16*)alloc((size_t)N * 1152 * 2);
  u16* s2      = (u16*)alloc((size_t)N * 2304 * 2);

  // ---- dtype detect ----
  detect_kernel<<<1, 256, 0, stream>>>((const u16*)x, dflag);

  // ---- zero counters + accumulators (one memset) ----
  hipMemsetAsync(cnt8, 0, zbytes, stream);

  // ---- CSR build keyed by (dst,rel) ----
  hist_kernel<<<(E + 255) / 256, 256, 0, stream>>>(ei, et, E, cnt8);
  segscan_kernel<<<1, 256, 0, stream>>>(cnt8, offs, cursor);
  bucket_kernel<<<(E + 255) / 256, 256, 0, stream>>>(ei, et, E, cursor, bucket);

  // ---- weight prep (transpose + both wpreps) ----
  transpose_kernel<<<dim3((N + 63) / 64, 2), 256, 0, stream>>>(emb, embT, N, 128, dflag);
  wprep_both_kernel<<<2304, 256, 0, stream>>>(comp1, basis1, root1, WT1,
                                              comp2, basis2, root2, WT2, dflag);

  // ---- stage A: h0 = relu(x @ emb) ----
  {
    int ktt = (N + 31) / 32;                 // 313
    int spA = 8;
    int tps = (ktt + spA - 1) / spA;         // 40
    gemm_kernel<<<dim3((N + 127) / 128, 1, spA), 256, 0, stream>>>(
        x, N, embT, N, N, 128, N, tps, ktt, h0f, dflag);
    finalize_kernel<<<(N * 128 / 4 + 255) / 256, 256, 0, stream>>>(
        h0f, N * 128 / 4, 127, (const void*)nullptr, h0, dflag);
  }

  // ---- layer 1: gather -> GEMM (z=4, atomic) -> finalize ----
  {
    gather1_kernel<<<N, 64, 0, stream>>>(h0, offs, bucket, s1);
    gemm_kernel<<<dim3((N + 127) / 128, 2, 4), 256, 0, stream>>>(
        s1, 1152, WT1, 1152, N, 256, 1152, 9, 36, h1f, (const int*)nullptr);
    finalize_kernel<<<(N * 256 / 4 + 255) / 256, 256, 0, stream>>>(
        h1f, N * 256 / 4, 255, bias1, h1, dflag);
  }

  // ---- layer 2: gather -> GEMM (z=8, atomic); bias+relu fused into decoder ----
  {
    gather2_kernel<<<N, 64, 0, stream>>>(h1, offs, bucket, s2);
    gemm_kernel<<<dim3((N + 127) / 128, 1, 8), 256, 0, stream>>>(
        s2, 2304, WT2, 2304, N, 128, 2304, 9, 72, h2f, (const int*)nullptr);
  }

  // ---- decoder + softmax (reads f32 h2f, applies bias2+relu) ----
  decoder_kernel<<<N / 4, 256, 0, stream>>>(h2f, wdec, bias2, d_out, dflag);
}

// Round 5
// 883.802 us; speedup vs baseline: 1.0372x; 1.0372x over previous
//
#include <hip/hip_runtime.h>

typedef unsigned short u16;
typedef unsigned int u32;
typedef __attribute__((ext_vector_type(8))) short bf16x8;
typedef __attribute__((ext_vector_type(4))) float f32x4;

#define N_NODES 10000
#define E_EDGES 640000

static __device__ __forceinline__ float b2f(u16 u) {
  union { u32 i; float f; } x; x.i = ((u32)u) << 16; return x.f;
}
static __device__ __forceinline__ u16 f2b(float f) {
  union { float f; u32 i; } x; x.f = f;
  u32 r = x.i + 0x7FFF + ((x.i >> 16) & 1);   // RNE
  return (u16)(r >> 16);
}
// dtype-flagged load: f32 ? float : bf16
static __device__ __forceinline__ float ldf(const void* p, size_t i, int f32) {
  return f32 ? ((const float*)p)[i] : b2f(((const u16*)p)[i]);
}

// ---------------- dtype detect: bf16 data has no exponent >= 140; fp32 low-halves do ----------------
__global__ __launch_bounds__(256) void detect_kernel(const u16* __restrict__ x, int* __restrict__ flag) {
  __shared__ int cnt_s;
  if (threadIdx.x == 0) cnt_s = 0;
  __syncthreads();
  int c = 0;
  for (int i = threadIdx.x; i < 4096; i += 256) {
    int e = (x[i] >> 7) & 255;
    if (e >= 140) c++;
  }
  atomicAdd(&cnt_s, c);
  __syncthreads();
  if (threadIdx.x == 0) flag[0] = (cnt_s > 64) ? 1 : 0;
}

// ---------------- CSR build keyed by (dst*8 + rel) ----------------
__global__ void hist_kernel(const int* __restrict__ ei, const int* __restrict__ et,
                            int E, int* __restrict__ cnt8) {
  int e = blockIdx.x * 256 + threadIdx.x;
  if (e < E) atomicAdd(&cnt8[ei[E + e] * 8 + et[e]], 1);
}

// fused: per-dst totals + exclusive scan + (dst,rel) segment offsets, one block
__global__ __launch_bounds__(256) void segscan_kernel(const int* __restrict__ cnt8,
                                                      int* __restrict__ offs,
                                                      int* __restrict__ cursor) {
  __shared__ int tmp[256];
  const int t = threadIdx.x;
  const int CH = (N_NODES + 255) / 256;   // 40
  const int d0 = t * CH;
  int s = 0;
  for (int j = 0; j < CH; j++) {
    int d = d0 + j;
    if (d < N_NODES) {
      #pragma unroll
      for (int r = 0; r < 8; r++) s += cnt8[d * 8 + r];
    }
  }
  tmp[t] = s;
  __syncthreads();
  for (int od = 1; od < 256; od <<= 1) {
    int a = (t >= od) ? tmp[t - od] : 0;
    __syncthreads();
    tmp[t] += a;
    __syncthreads();
  }
  int run = tmp[t] - s;   // exclusive prefix over this thread's chunk
  for (int j = 0; j < CH; j++) {
    int d = d0 + j;
    if (d < N_NODES) {
      #pragma unroll
      for (int r = 0; r < 8; r++) {
        offs[d * 8 + r] = run;
        cursor[d * 8 + r] = run;
        run += cnt8[d * 8 + r];
      }
    }
  }
  if (t == 255) offs[N_NODES * 8] = tmp[255];
}

__global__ void bucket_kernel(const int* __restrict__ ei, const int* __restrict__ et,
                              int E, int* __restrict__ cursor, int* __restrict__ bucket) {
  int e = blockIdx.x * 256 + threadIdx.x;
  if (e < E) {
    int seg = ei[E + e] * 8 + et[e];
    int pos = atomicAdd(&cursor[seg], 1);
    bucket[pos] = ei[e];   // src only; relation is the segment index
  }
}

// ---------------- transpose (emb -> embT as bf16) ----------------
__global__ void transpose_kernel(const void* __restrict__ in, u16* __restrict__ out,
                                 int R, int C, const int* __restrict__ dflag) {
  __shared__ u16 tile[64][65];
  const int f = dflag[0];
  int r0 = blockIdx.x * 64, c0 = blockIdx.y * 64;
  int t = threadIdx.x;
  #pragma unroll
  for (int k = 0; k < 16; k++) {
    int lin = t + k * 256; int rr = lin >> 6, cc = lin & 63;
    int gr = r0 + rr;
    tile[rr][cc] = (gr < R) ? f2b(ldf(in, (size_t)gr * C + c0 + cc, f)) : (u16)0;
  }
  __syncthreads();
  #pragma unroll
  for (int k = 0; k < 16; k++) {
    int lin = t + k * 256; int rr = lin >> 6, cc = lin & 63;
    int gc = r0 + cc;
    if (gc < R) out[(size_t)(c0 + rr) * R + gc] = tile[cc][rr];
  }
}

// ---------------- W-prep body: WT[o][kcat], kcat = r*I+i (basis rows) then I root rows ----------------
template<int I, int O>
static __device__ __forceinline__ void wprep_body(const void* comp, const void* basis,
                                                  const void* root, u16* WT,
                                                  int f, int blk) {
  const int Kcat = 9 * I;
  int idx = blk * 256 + threadIdx.x;
  if (idx >= Kcat * O) return;
  int o = idx % O;
  int kc = idx / O;
  float v;
  if (kc < 8 * I) {
    int r = kc / I, i = kc % I;
    float s = 0.f;
    #pragma unroll
    for (int b = 0; b < 8; b++)
      s += ldf(comp, r * 8 + b, f) * ldf(basis, ((size_t)b * I + i) * O + o, f);
    v = s;
  } else {
    int i = kc - 8 * I;
    v = ldf(root, (size_t)i * O + o, f);
  }
  WT[(size_t)o * Kcat + kc] = f2b(v);
}

// both layers' W-prep in one dispatch (blocks 0..1151 -> L1, 1152..2303 -> L2)
__global__ void wprep_both_kernel(const void* c1, const void* b1, const void* r1, u16* WT1,
                                  const void* c2, const void* b2, const void* r2, u16* WT2,
                                  const int* __restrict__ dflag) {
  const int f = dflag[0];
  int blk = blockIdx.x;
  if (blk < 1152) wprep_body<128, 256>(c1, b1, r1, WT1, f, blk);
  else            wprep_body<256, 128>(c2, b2, r2, WT2, f, blk - 1152);
}

// ---------------- gather layer 1: 64 threads, u32 channel-pairs, register accumulate ----------------
// s row layout (u16 units): [r*128 + i] = mean over relation-r in-edges; [1024 + i] = own h0 row
__global__ void gather1_kernel(const u16* __restrict__ h, const int* __restrict__ offs,
                               const int* __restrict__ bucket, u16* __restrict__ s) {
  const int d = blockIdx.x, t = threadIdx.x;   // 64 threads
  const u32* __restrict__ h32 = (const u32*)h;  // row stride 64
  u32* s32 = (u32*)s;
  const int sb = d * 8;
  const int b0 = offs[sb], bend = offs[sb + 8];
  const float inv = 1.0f / (float)((bend - b0) > 1 ? (bend - b0) : 1);
  const int base = d * 576;   // 1152/2
  #pragma unroll
  for (int r = 0; r < 8; r++) {
    int j = offs[sb + r], j1 = offs[sb + r + 1];
    float l0 = 0.f, h0a = 0.f, l1 = 0.f, h1a = 0.f, l2 = 0.f, h2a = 0.f, l3 = 0.f, h3a = 0.f;
    for (; j + 3 < j1; j += 4) {
      u32 v0 = h32[(size_t)bucket[j] * 64 + t];
      u32 v1 = h32[(size_t)bucket[j + 1] * 64 + t];
      u32 v2 = h32[(size_t)bucket[j + 2] * 64 + t];
      u32 v3 = h32[(size_t)bucket[j + 3] * 64 + t];
      l0 += b2f((u16)v0); h0a += b2f((u16)(v0 >> 16));
      l1 += b2f((u16)v1); h1a += b2f((u16)(v1 >> 16));
      l2 += b2f((u16)v2); h2a += b2f((u16)(v2 >> 16));
      l3 += b2f((u16)v3); h3a += b2f((u16)(v3 >> 16));
    }
    for (; j < j1; ++j) {
      u32 v = h32[(size_t)bucket[j] * 64 + t];
      l0 += b2f((u16)v); h0a += b2f((u16)(v >> 16));
    }
    float sl = (l0 + l1 + l2 + l3) * inv, sh = (h0a + h1a + h2a + h3a) * inv;
    s32[base + r * 64 + t] = (u32)f2b(sl) | ((u32)f2b(sh) << 16);
  }
  s32[base + 512 + t] = h32[(size_t)d * 64 + t];
}

// ---------------- gather layer 2: 64 threads, uint2 4-channel chunks ----------------
// s row layout (u16 units): [r*256 + i] mean; [2048 + i] own h1 row
__global__ void gather2_kernel(const u16* __restrict__ h, const int* __restrict__ offs,
                               const int* __restrict__ bucket, u16* __restrict__ s) {
  const int d = blockIdx.x, t = threadIdx.x;   // 64 threads
  const uint2* __restrict__ h64 = (const uint2*)h;  // row stride 64
  uint2* s64 = (uint2*)s;
  const int sb = d * 8;
  const int b0 = offs[sb], bend = offs[sb + 8];
  const float inv = 1.0f / (float)((bend - b0) > 1 ? (bend - b0) : 1);
  const int base = d * 576;   // 2304/4
  #pragma unroll
  for (int r = 0; r < 8; r++) {
    int j = offs[sb + r], j1 = offs[sb + r + 1];
    float4 A0 = {0.f, 0.f, 0.f, 0.f}, A1 = A0, A2 = A0, A3 = A0;
    for (; j + 3 < j1; j += 4) {
      uint2 v0 = h64[(size_t)bucket[j] * 64 + t];
      uint2 v1 = h64[(size_t)bucket[j + 1] * 64 + t];
      uint2 v2 = h64[(size_t)bucket[j + 2] * 64 + t];
      uint2 v3 = h64[(size_t)bucket[j + 3] * 64 + t];
      A0.x += b2f((u16)v0.x); A0.y += b2f((u16)(v0.x >> 16)); A0.z += b2f((u16)v0.y); A0.w += b2f((u16)(v0.y >> 16));
      A1.x += b2f((u16)v1.x); A1.y += b2f((u16)(v1.x >> 16)); A1.z += b2f((u16)v1.y); A1.w += b2f((u16)(v1.y >> 16));
      A2.x += b2f((u16)v2.x); A2.y += b2f((u16)(v2.x >> 16)); A2.z += b2f((u16)v2.y); A2.w += b2f((u16)(v2.y >> 16));
      A3.x += b2f((u16)v3.x); A3.y += b2f((u16)(v3.x >> 16)); A3.z += b2f((u16)v3.y); A3.w += b2f((u16)(v3.y >> 16));
    }
    for (; j < j1; ++j) {
      uint2 v = h64[(size_t)bucket[j] * 64 + t];
      A0.x += b2f((u16)v.x); A0.y += b2f((u16)(v.x >> 16)); A0.z += b2f((u16)v.y); A0.w += b2f((u16)(v.y >> 16));
    }
    float sx = (A0.x + A1.x + A2.x + A3.x) * inv;
    float sy = (A0.y + A1.y + A2.y + A3.y) * inv;
    float sz = (A0.z + A1.z + A2.z + A3.z) * inv;
    float sw = (A0.w + A1.w + A2.w + A3.w) * inv;
    uint2 o;
    o.x = (u32)f2b(sx) | ((u32)f2b(sy) << 16);
    o.y = (u32)f2b(sz) | ((u32)f2b(sw) << 16);
    s64[base + r * 64 + t] = o;
  }
  s64[base + 512 + t] = h64[(size_t)d * 64 + t];
}

// ---------------- MFMA GEMM: partials[split] = A[M,K] * BT[Nout,K]^T, 128x128 tiles ----------------
// A is bf16 unless (dflagA && dflagA[0]) -> fp32 elements, converted during staging.
__global__ __launch_bounds__(256) void gemm_kernel(
    const void* __restrict__ A, int lda,
    const u16* __restrict__ BT, int ldbt,
    int M, int Nout, int K,
    int tiles_per_split, int ktiles_total,
    float* __restrict__ partials,
    const int* __restrict__ dflagA) {
  __shared__ __align__(16) u16 As[128 * 32];
  __shared__ __align__(16) u16 Bs[128 * 32];
  const int f32A = dflagA ? dflagA[0] : 0;
  const int tid = threadIdx.x;
  const int wave = tid >> 6;
  const int lane = tid & 63;
  const int quad = lane >> 4;
  const int l16 = lane & 15;
  const int m0 = blockIdx.x * 128;
  const int n0 = blockIdx.y * 128;
  const int split = blockIdx.z;
  const int wm = (wave >> 1) * 64;
  const int wn = (wave & 1) * 64;

  int kt0 = split * tiles_per_split;
  int kt1 = kt0 + tiles_per_split;
  if (kt1 > ktiles_total) kt1 = ktiles_total;

  f32x4 acc[4][4];
  #pragma unroll
  for (int mi = 0; mi < 4; mi++)
    #pragma unroll
    for (int ni = 0; ni < 4; ni++) {
      f32x4 z = {0.f, 0.f, 0.f, 0.f};
      acc[mi][ni] = z;
    }

  for (int kt = kt0; kt < kt1; ++kt) {
    const int k0 = kt * 32;
    __syncthreads();
    #pragma unroll
    for (int i = 0; i < 2; ++i) {
      int c = tid + i * 256;
      int row = c >> 2, kc = c & 3;
      int kpos = k0 + kc * 8;
      // B tile (always bf16)
      uint4 vb = {0u, 0u, 0u, 0u};
      if (kpos < K) vb = *(const uint4*)(BT + (size_t)(n0 + row) * ldbt + kpos);
      *(uint4*)&Bs[(size_t)c * 8] = vb;
      // A tile
      uint4 va = {0u, 0u, 0u, 0u};
      if (kpos < K) {
        int ga = m0 + row; if (ga > M - 1) ga = M - 1;
        if (!f32A) {
          va = *(const uint4*)((const u16*)A + (size_t)ga * lda + kpos);
        } else {
          const float* Af = (const float*)A + (size_t)ga * lda + kpos;
          float4 f0 = ((const float4*)Af)[0];
          float4 f1 = ((const float4*)Af)[1];
          va.x = (u32)f2b(f0.x) | ((u32)f2b(f0.y) << 16);
          va.y = (u32)f2b(f0.z) | ((u32)f2b(f0.w) << 16);
          va.z = (u32)f2b(f1.x) | ((u32)f2b(f1.y) << 16);
          va.w = (u32)f2b(f1.z) | ((u32)f2b(f1.w) << 16);
        }
      }
      *(uint4*)&As[(size_t)c * 8] = va;
    }
    __syncthreads();

    bf16x8 af[4], bfr[4];
    #pragma unroll
    for (int mi = 0; mi < 4; mi++)
      af[mi] = *(const bf16x8*)&As[(size_t)(wm + mi * 16 + l16) * 32 + quad * 8];
    #pragma unroll
    for (int ni = 0; ni < 4; ni++)
      bfr[ni] = *(const bf16x8*)&Bs[(size_t)(wn + ni * 16 + l16) * 32 + quad * 8];
    #pragma unroll
    for (int mi = 0; mi < 4; mi++)
      #pragma unroll
      for (int ni = 0; ni < 4; ni++)
        acc[mi][ni] = __builtin_amdgcn_mfma_f32_16x16x32_bf16(af[mi], bfr[ni], acc[mi][ni], 0, 0, 0);
  }

  #pragma unroll
  for (int mi = 0; mi < 4; mi++)
    #pragma unroll
    for (int ni = 0; ni < 4; ni++)
      #pragma unroll
      for (int jj = 0; jj < 4; jj++) {
        int row = m0 + wm + mi * 16 + quad * 4 + jj;
        int col = n0 + wn + ni * 16 + l16;
        if (row < M) partials[((size_t)split * M + row) * Nout + col] = acc[mi][ni][jj];
      }
}

// ---------------- finalize: sum S split-partials (+bias) -> relu -> bf16, float4/thread ----------------
__global__ void finalize_kernel(const float* __restrict__ partials, int S, int count4,
                                int nmask, const void* __restrict__ bias, u16* __restrict__ out,
                                const int* __restrict__ dflag) {
  int i = blockIdx.x * 256 + threadIdx.x;
  if (i >= count4) return;
  const int f = dflag[0];
  float4 v = {0.f, 0.f, 0.f, 0.f};
  for (int z = 0; z < S; z++) {
    float4 p = ((const float4*)(partials + (size_t)z * count4 * 4))[i];
    v.x += p.x; v.y += p.y; v.z += p.z; v.w += p.w;
  }
  if (bias) {
    int c = (i * 4) & nmask;
    v.x += ldf(bias, c, f);
    v.y += ldf(bias, c + 1, f);
    v.z += ldf(bias, c + 2, f);
    v.w += ldf(bias, c + 3, f);
  }
  v.x = fmaxf(v.x, 0.f); v.y = fmaxf(v.y, 0.f); v.z = fmaxf(v.z, 0.f); v.w = fmaxf(v.w, 0.f);
  ushort4 o;
  o.x = f2b(v.x); o.y = f2b(v.y); o.z = f2b(v.z); o.w = f2b(v.w);
  *(ushort4*)(out + (size_t)i * 4) = o;
}

// ---------------- decoder: softmax(relu(sum_z p2 + bias2) @ wdec); output dtype follows flag ----------------
__global__ __launch_bounds__(256) void decoder_kernel(const float* __restrict__ p2, int S,
                                                      const void* __restrict__ wdec,
                                                      const void* __restrict__ bias2,
                                                      void* __restrict__ out,
                                                      const int* __restrict__ dflag) {
  __shared__ float w[128 * 32];
  __shared__ float hrow[4][128];
  const int f = dflag[0];
  int t = threadIdx.x;
  for (int i = t; i < 128 * 32; i += 256) w[i] = ldf(wdec, i, f);
  int wv = t >> 6, lane = t & 63;
  int n = blockIdx.x * 4 + wv;   // grid 2500 * 4 waves = 10000 exactly
  float v0 = 0.f, v1 = 0.f;
  for (int z = 0; z < S; z++) {
    const float* row = p2 + (size_t)z * N_NODES * 128 + (size_t)n * 128;
    v0 += row[lane * 2];
    v1 += row[lane * 2 + 1];
  }
  v0 += ldf(bias2, lane * 2, f);
  v1 += ldf(bias2, lane * 2 + 1, f);
  hrow[wv][lane * 2]     = fmaxf(v0, 0.f);
  hrow[wv][lane * 2 + 1] = fmaxf(v1, 0.f);
  __syncthreads();
  int half = lane >> 5, c = lane & 31;
  float sum = 0.f;
  #pragma unroll 8
  for (int k = 0; k < 64; k++) sum += hrow[wv][half * 64 + k] * w[(half * 64 + k) * 32 + c];
  sum += __shfl_xor(sum, 32);
  float mx = sum;
  #pragma unroll
  for (int m = 16; m >= 1; m >>= 1) mx = fmaxf(mx, __shfl_xor(mx, m));
  float e = __expf(sum - mx);
  float tot = e;
  #pragma unroll
  for (int m = 16; m >= 1; m >>= 1) tot += __shfl_xor(tot, m);
  float p = e / tot;
  if (half == 0) {
    if (f) ((float*)out)[(size_t)n * 32 + c] = p;
    else   ((u16*)out)[(size_t)n * 32 + c] = f2b(p);
  }
}

extern "C" void kernel_launch(void* const* d_in, const int* in_sizes, int n_in,
                              void* d_out, int out_size, void* d_ws, size_t ws_size,
                              hipStream_t stream) {
  const void* x      = d_in[0];
  const int* ei      = (const int*)d_in[1];
  const int* et      = (const int*)d_in[2];
  const void* emb    = d_in[3];
  const void* comp1  = d_in[4];
  const void* basis1 = d_in[5];
  const void* root1  = d_in[6];
  const void* bias1  = d_in[7];
  const void* comp2  = d_in[8];
  const void* basis2 = d_in[9];
  const void* root2  = d_in[10];
  const void* bias2  = d_in[11];
  const void* wdec   = d_in[12];

  const int N = N_NODES, E = E_EDGES;
  const int NSEG = N * 8;
  auto AL = [](size_t b) -> size_t { return (b + 255) & ~(size_t)255; };

  // ---- persistent arena ----
  char* base = (char*)d_ws;
  size_t off = 0;
  auto alloc = [&](size_t b) -> char* { char* p = base + off; off += AL(b); return p; };
  int* dflag   = (int*)alloc(4);
  int* offs    = (int*)alloc((size_t)(NSEG + 1) * 4);
  int* cursor  = (int*)alloc((size_t)NSEG * 4);
  int* bucket  = (int*)alloc((size_t)E * 4);
  u16* h0      = (u16*)alloc((size_t)N * 128 * 2);
  u16* h1      = (u16*)alloc((size_t)N * 256 * 2);
  int* cnt8    = (int*)alloc((size_t)NSEG * 4);        // memset target
  u16* WT1     = (u16*)alloc((size_t)256 * 1152 * 2);
  u16* WT2     = (u16*)alloc((size_t)128 * 2304 * 2);
  u16* embT    = (u16*)alloc((size_t)128 * N * 2);
  u16* s1      = (u16*)alloc((size_t)N * 1152 * 2);
  u16* s2      = (u16*)alloc((size_t)N * 2304 * 2);
  float* pA    = (float*)alloc((size_t)8 * N * 128 * 4);
  float* p1    = (float*)alloc((size_t)2 * N * 256 * 4);
  float* p2    = (float*)alloc((size_t)4 * N * 128 * 4);

  // ---- dtype detect ----
  detect_kernel<<<1, 256, 0, stream>>>((const u16*)x, dflag);

  // ---- zero edge counters ----
  hipMemsetAsync(cnt8, 0, (size_t)NSEG * 4, stream);

  // ---- CSR build keyed by (dst,rel) ----
  hist_kernel<<<(E + 255) / 256, 256, 0, stream>>>(ei, et, E, cnt8);
  segscan_kernel<<<1, 256, 0, stream>>>(cnt8, offs, cursor);
  bucket_kernel<<<(E + 255) / 256, 256, 0, stream>>>(ei, et, E, cursor, bucket);

  // ---- weight prep (transpose + both wpreps) ----
  transpose_kernel<<<dim3((N + 63) / 64, 2), 256, 0, stream>>>(emb, embT, N, 128, dflag);
  wprep_both_kernel<<<2304, 256, 0, stream>>>(comp1, basis1, root1, WT1,
                                              comp2, basis2, root2, WT2, dflag);

  // ---- stage A: h0 = relu(x @ emb), split-K=8 via partials ----
  {
    int ktt = (N + 31) / 32;                 // 313
    int spA = 8;
    int tps = (ktt + spA - 1) / spA;         // 40
    gemm_kernel<<<dim3((N + 127) / 128, 1, spA), 256, 0, stream>>>(
        x, N, embT, N, N, 128, N, tps, ktt, pA, dflag);
    finalize_kernel<<<(N * 128 / 4 + 255) / 256, 256, 0, stream>>>(
        pA, spA, N * 128 / 4, 127, (const void*)nullptr, h0, dflag);
  }

  // ---- layer 1: gather -> GEMM (z=2, partials) -> finalize ----
  {
    gather1_kernel<<<N, 64, 0, stream>>>(h0, offs, bucket, s1);
    gemm_kernel<<<dim3((N + 127) / 128, 2, 2), 256, 0, stream>>>(
        s1, 1152, WT1, 1152, N, 256, 1152, 18, 36, p1, (const int*)nullptr);
    finalize_kernel<<<(N * 256 / 4 + 255) / 256, 256, 0, stream>>>(
        p1, 2, N * 256 / 4, 255, bias1, h1, dflag);
  }

  // ---- layer 2: gather -> GEMM (z=4, partials); split-sum + bias + relu fused into decoder ----
  {
    gather2_kernel<<<N, 64, 0, stream>>>(h1, offs, bucket, s2);
    gemm_kernel<<<dim3((N + 127) / 128, 1, 4), 256, 0, stream>>>(
        s2, 2304, WT2, 2304, N, 128, 2304, 18, 72, p2, (const int*)nullptr);
  }

  // ---- decoder + softmax (sums layer-2 splits, applies bias2+relu) ----
  decoder_kernel<<<N / 4, 256, 0, stream>>>(p2, 4, wdec, bias2, d_out, dflag);
}